// Round 1
// baseline (15831.499 us; speedup 1.0000x reference)
//
#include <hip/hip_runtime.h>
#include <hip/hip_cooperative_groups.h>
#include <math.h>

namespace cg = cooperative_groups;

typedef unsigned short u16;
typedef __bf16 bf16x8 __attribute__((ext_vector_type(8)));
typedef float f32x4 __attribute__((ext_vector_type(4)));
typedef unsigned short u16x8 __attribute__((ext_vector_type(8)));

#define NBLK 256
#define NTHR 256
#define BB 1024   // batch
#define TT 256    // time steps
#define EE 512    // embed dim
#define UU 1024   // hidden dim

__device__ __forceinline__ u16 f2bf(float f) {
  unsigned u = __builtin_bit_cast(unsigned, f);
  u += 0x7fffu + ((u >> 16) & 1u);   // RNE
  return (u16)(u >> 16);
}
__device__ __forceinline__ float bf2f(u16 h) {
  return __builtin_bit_cast(float, ((unsigned)h) << 16);
}
__device__ __forceinline__ float fast_tanh(float x) {
  x = fminf(fmaxf(x, -15.f), 15.f);
  float e = __expf(2.f * x);
  return (e - 1.f) / (e + 1.f);
}

struct __align__(16) Smem {
  u16 A[64][72];   // A tile: 64 rows (batch) x 64 K, padded to 72
  u16 B[64][72];   // B tile: 64 rows (out col n) x 64 K (weights pre-transposed)
  int idx[64];     // embedding row indices for this block's batch rows
};

struct St { u16x8 lo, hi; };

template<bool EMB, int KLOW>
__device__ __forceinline__ St loadA(const float* __restrict__ emb,
    const Smem& sm, const u16* __restrict__ Alow, const u16* __restrict__ Ahigh,
    int M0, int kglob, int r, int seg)
{
  St s;
  const int kk = kglob + seg * 16;
  if (kglob < KLOW) {
    if (EMB) {
      const f32x4* p = (const f32x4*)(emb + (long long)sm.idx[r] * EE + kk);
      f32x4 f0 = p[0], f1 = p[1], f2 = p[2], f3 = p[3];
      u16x8 lo, hi;
#pragma unroll
      for (int j = 0; j < 4; ++j) {
        lo[j]     = f2bf(f0[j]);
        lo[j + 4] = f2bf(f1[j]);
        hi[j]     = f2bf(f2[j]);
        hi[j + 4] = f2bf(f3[j]);
      }
      s.lo = lo; s.hi = hi;
    } else {
      const u16x8* p = (const u16x8*)(Alow + (long long)(M0 + r) * KLOW + kk);
      s.lo = p[0]; s.hi = p[1];
    }
  } else {
    const u16x8* p = (const u16x8*)(Ahigh + (long long)(M0 + r) * UU + (kk - KLOW));
    s.lo = p[0]; s.hi = p[1];
  }
  return s;
}

template<int KTOT>
__device__ __forceinline__ St loadB(const u16* __restrict__ Bt, int N0, int kglob, int r, int seg) {
  const int kk = kglob + seg * 16;
  const u16x8* p = (const u16x8*)(Bt + (long long)(N0 + r) * KTOT + kk);
  St s; s.lo = p[0]; s.hi = p[1];
  return s;
}

// One GEMM phase: C[1024x1024] = A[1024xKTOT] @ B[KTOTx1024]; out = tanh(C + bias) as bf16.
// A = [low-source | high-source] split at KLOW. B given pre-transposed bf16 [1024][KTOT].
template<bool EMB, int KTOT, int KLOW>
__device__ __forceinline__ void gemm_phase(Smem& sm,
    const float* __restrict__ emb, const int* __restrict__ inputs, int t,
    const u16* __restrict__ Alow, const u16* __restrict__ Ahigh,
    const u16* __restrict__ Bt, const float* __restrict__ bias,
    u16* __restrict__ Hout, int M0, int N0)
{
  const int tid = threadIdx.x;
  const int r = tid >> 2, seg = tid & 3;   // staging map: row r, 16-elem segment seg

  if (EMB) {
    if (tid < 64) sm.idx[tid] = inputs[(M0 + tid) * TT + t];
  }
  __syncthreads();   // idx visible + previous phase done with LDS

  const int lane = tid & 63, wid = tid >> 6;
  const int wr = (wid >> 1) * 32, wc = (wid & 1) * 32;  // wave tile origin (2x2 waves of 32x32)
  const int q = lane >> 4, l16 = lane & 15;

  f32x4 c00 = {0.f, 0.f, 0.f, 0.f};
  f32x4 c01 = {0.f, 0.f, 0.f, 0.f};
  f32x4 c10 = {0.f, 0.f, 0.f, 0.f};
  f32x4 c11 = {0.f, 0.f, 0.f, 0.f};

  St a_cur = loadA<EMB, KLOW>(emb, sm, Alow, Ahigh, M0, 0, r, seg);
  St b_cur = loadB<KTOT>(Bt, N0, 0, r, seg);

  const int NC = KTOT / 64;
  for (int c = 0; c < NC; ++c) {
    *(u16x8*)&sm.A[r][seg * 16]     = a_cur.lo;
    *(u16x8*)&sm.A[r][seg * 16 + 8] = a_cur.hi;
    *(u16x8*)&sm.B[r][seg * 16]     = b_cur.lo;
    *(u16x8*)&sm.B[r][seg * 16 + 8] = b_cur.hi;
    if (c + 1 < NC) {
      a_cur = loadA<EMB, KLOW>(emb, sm, Alow, Ahigh, M0, (c + 1) * 64, r, seg);
      b_cur = loadB<KTOT>(Bt, N0, (c + 1) * 64, r, seg);
    }
    __syncthreads();   // staged tile visible
#pragma unroll
    for (int kk = 0; kk < 64; kk += 32) {
      bf16x8 a0 = __builtin_bit_cast(bf16x8, *(const u16x8*)&sm.A[wr + l16][kk + q * 8]);
      bf16x8 a1 = __builtin_bit_cast(bf16x8, *(const u16x8*)&sm.A[wr + 16 + l16][kk + q * 8]);
      bf16x8 b0 = __builtin_bit_cast(bf16x8, *(const u16x8*)&sm.B[wc + l16][kk + q * 8]);
      bf16x8 b1 = __builtin_bit_cast(bf16x8, *(const u16x8*)&sm.B[wc + 16 + l16][kk + q * 8]);
      c00 = __builtin_amdgcn_mfma_f32_16x16x32_bf16(a0, b0, c00, 0, 0, 0);
      c01 = __builtin_amdgcn_mfma_f32_16x16x32_bf16(a0, b1, c01, 0, 0, 0);
      c10 = __builtin_amdgcn_mfma_f32_16x16x32_bf16(a1, b0, c10, 0, 0, 0);
      c11 = __builtin_amdgcn_mfma_f32_16x16x32_bf16(a1, b1, c11, 0, 0, 0);
    }
    __syncthreads();   // compute done before next overwrite
  }

  // epilogue: bias + tanh + bf16 store. D layout: col=lane&15, row=quad*4+reg.
  const float bs0 = bias[N0 + wc + l16];
  const float bs1 = bias[N0 + wc + 16 + l16];
#pragma unroll
  for (int i = 0; i < 2; ++i) {
    f32x4 v0 = i ? c10 : c00;
    f32x4 v1 = i ? c11 : c01;
#pragma unroll
    for (int rr = 0; rr < 4; ++rr) {
      int row = M0 + wr + i * 16 + q * 4 + rr;
      u16* o = Hout + (long long)row * UU + (N0 + wc + l16);
      o[0]  = f2bf(fast_tanh(v0[rr] + bs0));
      o[16] = f2bf(fast_tanh(v1[rr] + bs1));
    }
  }
}

__global__ __launch_bounds__(NTHR, 1)
void rnn_kernel(const int* __restrict__ inputs, const float* __restrict__ emb,
    const float* __restrict__ W0, const float* __restrict__ U0, const float* __restrict__ b0,
    const float* __restrict__ W1, const float* __restrict__ U1, const float* __restrict__ b1,
    const float* __restrict__ Wout, const float* __restrict__ bout,
    float* __restrict__ out,
    u16* __restrict__ Wt0, u16* __restrict__ Wt1,
    u16* __restrict__ h0, u16* __restrict__ h1)
{
  __shared__ Smem sm;
  cg::grid_group grid = cg::this_grid();
  const int tid = threadIdx.x;
  const int bid = blockIdx.x;

  // ---- startup: convert+transpose weights to bf16 [N][K], zero initial states ----
#pragma unroll 1
  for (int rr = 0; rr < 4; ++rr) {
    const int n = bid * 4 + rr;
    for (int k = tid; k < 1536; k += NTHR)
      Wt0[(long long)n * 1536 + k] =
          f2bf(k < 512 ? W0[(long long)k * UU + n] : U0[(long long)(k - 512) * UU + n]);
    for (int k = tid; k < 2048; k += NTHR)
      Wt1[(long long)n * 2048 + k] =
          f2bf(k < 1024 ? W1[(long long)k * UU + n] : U1[(long long)(k - 1024) * UU + n]);
  }
  {
    const u16x8 z = {0, 0, 0, 0, 0, 0, 0, 0};
    u16x8* p0 = (u16x8*)h0;   // zero buffer 0 of each state
    u16x8* p1 = (u16x8*)h1;
    const int nv = (BB * UU) / 8;
    for (int i = bid * NTHR + tid; i < nv; i += NBLK * NTHR) { p0[i] = z; p1[i] = z; }
  }
  grid.sync();

  // block -> 64x64 C tile, XCD-swizzled (2 col-groups per XCD keep B stripe L2-hot)
  const int xcd = bid & 7, i8 = bid >> 3;
  const int N0 = (xcd * 2 + (i8 & 1)) * 64;
  const int M0 = (i8 >> 1) * 64;
  const int HN = BB * UU;

  for (int t = 0; t < TT; ++t) {
    const u16* h0c = h0 + (t & 1) * HN;
    u16*       h0n = h0 + ((t + 1) & 1) * HN;
    const u16* h1c = h1 + (t & 1) * HN;
    u16*       h1n = h1 + ((t + 1) & 1) * HN;
    // h0' = tanh([x_t | h0] @ [W0;U0] + b0)
    gemm_phase<true, 1536, 512>(sm, emb, inputs, t, (const u16*)nullptr, h0c, Wt0, b0, h0n, M0, N0);
    grid.sync();
    // h1' = tanh([h0' | h1] @ [W1;U1] + b1)   (double-buffered states => 1 sync/step)
    gemm_phase<false, 2048, 1024>(sm, emb, inputs, t, h0n, h1c, Wt1, b1, h1n, M0, N0);
  }
  grid.sync();

  // ---- output: sigmoid(h1 @ Wout + bout), one wave per 16 rows ----
  if (bid < 16) {
    const u16* hf = h1;   // TT even -> final h1 in buffer 0
    const int wid = tid >> 6, lane = tid & 63;
    int m = (bid * 4 + wid) * 16;
    for (int rr = 0; rr < 16; ++rr, ++m) {
      const u16x8* hv = (const u16x8*)(hf + (long long)m * UU + lane * 16);
      u16x8 lo = hv[0], hi = hv[1];
      const f32x4* wv = (const f32x4*)(Wout + lane * 16);
      f32x4 w0 = wv[0], w1 = wv[1], w2 = wv[2], w3 = wv[3];
      float s = 0.f;
#pragma unroll
      for (int j = 0; j < 4; ++j) {
        s += bf2f(lo[j]) * w0[j];
        s += bf2f(lo[j + 4]) * w1[j];
        s += bf2f(hi[j]) * w2[j];
        s += bf2f(hi[j + 4]) * w3[j];
      }
#pragma unroll
      for (int off = 32; off > 0; off >>= 1) s += __shfl_down(s, off);
      if (lane == 0) out[m] = 1.f / (1.f + expf(-(s + bout[0])));
    }
  }
}

extern "C" void kernel_launch(void* const* d_in, const int* in_sizes, int n_in,
                              void* d_out, int out_size, void* d_ws, size_t ws_size,
                              hipStream_t stream)
{
  (void)in_sizes; (void)n_in; (void)out_size; (void)ws_size;
  const int*   inputs = (const int*)d_in[0];
  const float* emb    = (const float*)d_in[1];
  const float* W0     = (const float*)d_in[2];
  const float* U0     = (const float*)d_in[3];
  const float* b0     = (const float*)d_in[4];
  const float* W1     = (const float*)d_in[5];
  const float* U1     = (const float*)d_in[6];
  const float* b1     = (const float*)d_in[7];
  const float* Wout   = (const float*)d_in[8];
  const float* bout   = (const float*)d_in[9];
  float* out = (float*)d_out;

  // ws layout (bf16): Wt0 [1024][1536], Wt1 [1024][2048], h0 [2][1024*1024], h1 [2][1024*1024]
  u16* Wt0 = (u16*)d_ws;
  u16* Wt1 = Wt0 + (size_t)1024 * 1536;
  u16* h0  = Wt1 + (size_t)1024 * 2048;
  u16* h1  = h0 + (size_t)2 * 1024 * 1024;

  void* args[] = { &inputs, &emb, &W0, &U0, &b0, &W1, &U1, &b1, &Wout, &bout,
                   &out, &Wt0, &Wt1, &h0, &h1 };
  hipLaunchCooperativeKernel((void*)rnn_kernel, dim3(NBLK), dim3(NTHR), args, 0, stream);
}